// Round 12
// baseline (60.440 us; speedup 1.0000x reference)
//
#include <hip/hip_runtime.h>

#define BN_EPS 1e-5f
#define NEG_SLOPE 0.2f

constexpr int B_ = 16384;
constexpr int Din = 4096;
constexpr int Dout = 256;
constexpr int D_RANK = 20;
constexpr int NPART = 1024;   // one partial per matvec block (16 rows each)

typedef float f4 __attribute__((ext_vector_type(4)));

// ws layout (floats):
// [0, 4096)        : Bv
// [4096, 4352)     : A
// [4352, 20736)    : t (16384)
// [20736, 24832)   : partials: 1024 x double2 (byte 82944, 16B-aligned)
#define WS_BV 0
#define WS_A 4096
#define WS_T 4352
#define WS_PART 20736

// ---------------- Kernel 1: synthesize A (Dout) and Bv (Din) -----------------
__global__ __launch_bounds__(256) void k_synth(
    const float* __restrict__ alphas, const float* __restrict__ cA,
    const float* __restrict__ cB, float* __restrict__ A, float* __restrict__ Bv) {
  __shared__ float al[D_RANK];
  int tid = threadIdx.x;
  if (tid < D_RANK) al[tid] = alphas[tid];
  __syncthreads();
  if (blockIdx.x == 0) {
    float s = 0.f;
#pragma unroll
    for (int d = 0; d < D_RANK; ++d) s += al[d] * cA[d * Dout + tid];
    A[tid] = s;
  } else {
    int k = (blockIdx.x - 1) * 256 + tid;
    float s = 0.f;
#pragma unroll
    for (int d = 0; d < D_RANK; ++d) s += al[d] * cB[k * D_RANK + d];
    Bv[k] = s;
  }
}

// ---------------- Kernel 2: t = x @ Bv + per-block (sum, sumsq) partial ------
// 1024 threads = 16 waves, one row per wave; grid 1024 (2 blocks/CU, same
// 32 waves/CU as before, but HALF the Bv-staging prologues and tails).
// First x-iteration is prefetched BEFORE the staging barrier so the HBM
// latency overlaps the Bv L2 loads. No fence/atomic (round 8: 3x slowdown).
__global__ __launch_bounds__(1024) void k_matvec(
    const float* __restrict__ x, const float* __restrict__ Bv,
    float* __restrict__ t, double2* __restrict__ partials) {
  __shared__ f4 bvs[Din / 4];   // 16 KiB
  __shared__ float tv[16];
  int tid = threadIdx.x;
  int wave = tid >> 6;   // 0..15
  int lane = tid & 63;
  int row = blockIdx.x * 16 + wave;
  const f4* xr = reinterpret_cast<const f4*>(x + (size_t)row * Din);

  // prefetch it=0 x data; issue concurrently with Bv staging loads
  f4 px0 = xr[lane];
  f4 px1 = xr[64 + lane];
  const f4* bv = reinterpret_cast<const f4*>(Bv);
  bvs[tid] = bv[tid];
  __syncthreads();

  f4 ba = bvs[lane];
  f4 bb = bvs[64 + lane];
  float acc0 = px0.x * ba.x + px0.y * ba.y + px0.z * ba.z + px0.w * ba.w;
  float acc1 = px1.x * bb.x + px1.y * bb.y + px1.z * bb.z + px1.w * bb.w;
#pragma unroll
  for (int it = 1; it < 8; ++it) {
    f4 xa = xr[it * 128 + lane];
    f4 xb = xr[it * 128 + 64 + lane];
    ba = bvs[it * 128 + lane];
    bb = bvs[it * 128 + 64 + lane];
    acc0 += xa.x * ba.x + xa.y * ba.y + xa.z * ba.z + xa.w * ba.w;
    acc1 += xb.x * bb.x + xb.y * bb.y + xb.z * bb.z + xb.w * bb.w;
  }
  float acc = acc0 + acc1;
#pragma unroll
  for (int off = 32; off > 0; off >>= 1) acc += __shfl_down(acc, off, 64);
  if (lane == 0) {
    t[row] = acc;
    tv[wave] = acc;
  }
  __syncthreads();
  if (tid == 0) {
    double s = 0.0, q = 0.0;
#pragma unroll
    for (int w = 0; w < 16; ++w) {
      double v = (double)tv[w];
      s += v;
      q += v * v;
    }
    partials[blockIdx.x] = make_double2(s, q);
  }
}

// ---------------- Kernel 3: finish = wave0-reduce + BN + leaky + write -------
// 512 blocks x 512 threads, 32 rows each; all co-resident (2/CU), so the
// redundant per-block stats reduction is paid once, in parallel. Wave 0
// reduces all 1024 partials: 16 coalesced L2 rounds + 6-round shfl tree --
// no __syncthreads inside, no fences/atomics. Fixed order -> deterministic.
__global__ __launch_bounds__(512) void k_finish(
    const float* __restrict__ t, const double2* __restrict__ partials,
    const float* __restrict__ A, const float* __restrict__ gamma,
    const float* __restrict__ beta, float* __restrict__ out) {
  __shared__ double red[2];     // mean, var
  __shared__ float ss[Dout];
  __shared__ float bs[Dout];
  __shared__ float ts[32];
  int tid = threadIdx.x;
  if (tid >= 64 && tid < 96) ts[tid - 64] = t[blockIdx.x * 32 + (tid - 64)];
  if (tid < 64) {
    double ls = 0.0, lq = 0.0;
#pragma unroll
    for (int i = 0; i < NPART / 64; ++i) {   // 16 independent coalesced rounds
      double2 p = partials[tid + i * 64];
      ls += p.x;
      lq += p.y;
    }
#pragma unroll
    for (int off = 32; off > 0; off >>= 1) {
      ls += __shfl_down(ls, off, 64);
      lq += __shfl_down(lq, off, 64);
    }
    if (tid == 0) {
      double mean = ls / (double)B_;
      red[0] = mean;
      red[1] = lq / (double)B_ - mean * mean;  // biased, matches jnp.var
    }
  }
  __syncthreads();
  double mean = red[0];
  double var = red[1];
  if (tid < Dout) {
    float a = A[tid];
    float inv = rsqrtf((float)((double)a * (double)a * var) + BN_EPS);
    float sj = a * gamma[tid] * inv;
    ss[tid] = sj;
    bs[tid] = beta[tid] - (float)mean * sj;
  }
  __syncthreads();
#pragma unroll
  for (int j = 0; j < 4; ++j) {
    int idx = j * 512 + tid;     // 0..2047 = 32 rows x 64 f4
    int rin = idx >> 6;
    int c4 = idx & 63;
    int row = blockIdx.x * 32 + rin;
    float tvv = ts[rin];
    f4 sv = *reinterpret_cast<const f4*>(&ss[c4 * 4]);
    f4 bv = *reinterpret_cast<const f4*>(&bs[c4 * 4]);
    f4 o;
    o.x = tvv * sv.x + bv.x; o.x = (o.x >= 0.f) ? o.x : NEG_SLOPE * o.x;
    o.y = tvv * sv.y + bv.y; o.y = (o.y >= 0.f) ? o.y : NEG_SLOPE * o.y;
    o.z = tvv * sv.z + bv.z; o.z = (o.z >= 0.f) ? o.z : NEG_SLOPE * o.z;
    o.w = tvv * sv.w + bv.w; o.w = (o.w >= 0.f) ? o.w : NEG_SLOPE * o.w;
    reinterpret_cast<f4*>(out)[(size_t)row * (Dout / 4) + c4] = o;
  }
}

extern "C" void kernel_launch(void* const* d_in, const int* in_sizes, int n_in,
                              void* d_out, int out_size, void* d_ws, size_t ws_size,
                              hipStream_t stream) {
  const float* x      = (const float*)d_in[0];
  const float* alphas = (const float*)d_in[1];
  const float* cA     = (const float*)d_in[2];
  const float* cB     = (const float*)d_in[3];
  // d_in[4] = linear_bias: cancels exactly inside BatchNorm (out - mean).
  const float* gamma  = (const float*)d_in[5];
  const float* beta   = (const float*)d_in[6];
  float* out = (float*)d_out;
  float* ws  = (float*)d_ws;

  float*   Bv       = ws + WS_BV;
  float*   A        = ws + WS_A;
  float*   t        = ws + WS_T;
  double2* partials = reinterpret_cast<double2*>(ws + WS_PART);

  k_synth<<<1 + Din / 256, 256, 0, stream>>>(alphas, cA, cB, A, Bv);
  k_matvec<<<NPART, 1024, 0, stream>>>(x, Bv, t, partials);
  k_finish<<<B_ / 32, 512, 0, stream>>>(t, partials, A, gamma, beta, out);
}

// Round 13
// 56.483 us; speedup vs baseline: 1.0701x; 1.0701x over previous
//
#include <hip/hip_runtime.h>

#define BN_EPS 1e-5f
#define NEG_SLOPE 0.2f

constexpr int B_ = 16384;
constexpr int Din = 4096;
constexpr int Dout = 256;
constexpr int D_RANK = 20;
constexpr int NPART = 2048;   // one partial per matvec block (8 rows each)

typedef float f4 __attribute__((ext_vector_type(4)));

// ws layout (floats):
// [0, 4096)        : Bv
// [4096, 4352)     : A
// [4352, 20736)    : t (16384)
// [20736, 28928)   : partials: 2048 x double2 (byte 82944, 16B-aligned)
#define WS_BV 0
#define WS_A 4096
#define WS_T 4352
#define WS_PART 20736

// ---------------- Kernel 1: synthesize A (Dout) and Bv (Din) -----------------
__global__ __launch_bounds__(256) void k_synth(
    const float* __restrict__ alphas, const float* __restrict__ cA,
    const float* __restrict__ cB, float* __restrict__ A, float* __restrict__ Bv) {
  __shared__ float al[D_RANK];
  int tid = threadIdx.x;
  if (tid < D_RANK) al[tid] = alphas[tid];
  __syncthreads();
  if (blockIdx.x == 0) {
    float s = 0.f;
#pragma unroll
    for (int d = 0; d < D_RANK; ++d) s += al[d] * cA[d * Dout + tid];
    A[tid] = s;
  } else {
    int k = (blockIdx.x - 1) * 256 + tid;
    float s = 0.f;
#pragma unroll
    for (int d = 0; d < D_RANK; ++d) s += al[d] * cB[k * D_RANK + d];
    Bv[k] = s;
  }
}

// ---------------- Kernel 2: t = x @ Bv + per-block (sum, sumsq) partial ------
// Round-11 geometry (proven 56.1 us): 512 threads = 8 waves, one row/wave,
// grid 2048 = 4 blocks/CU (r12 lesson: bigger blocks at same waves/CU lose).
// Single change vs r11: the it=0 x loads are issued BEFORE the Bv-staging
// barrier, so each block's first HBM latency (~900 cy) overlaps the 16 KiB
// LDS staging instead of serializing behind it. No fence/atomic (r8: 3x).
__global__ __launch_bounds__(512) void k_matvec(
    const float* __restrict__ x, const float* __restrict__ Bv,
    float* __restrict__ t, double2* __restrict__ partials) {
  __shared__ f4 bvs[Din / 4];   // 16 KiB
  int tid = threadIdx.x;
  int wave = tid >> 6;   // 0..7
  int lane = tid & 63;
  int row = blockIdx.x * 8 + wave;
  const f4* xr = reinterpret_cast<const f4*>(x + (size_t)row * Din);

  // prefetch it=0 x data; issues concurrently with the Bv staging loads
  f4 px0 = xr[lane];
  f4 px1 = xr[64 + lane];
  const f4* bv = reinterpret_cast<const f4*>(Bv);
  bvs[tid] = bv[tid];
  bvs[tid + 512] = bv[tid + 512];
  __syncthreads();

  f4 ba = bvs[lane];
  f4 bb = bvs[64 + lane];
  float acc0 = px0.x * ba.x + px0.y * ba.y + px0.z * ba.z + px0.w * ba.w;
  float acc1 = px1.x * bb.x + px1.y * bb.y + px1.z * bb.z + px1.w * bb.w;
#pragma unroll
  for (int it = 1; it < 8; ++it) {
    f4 xa = xr[it * 128 + lane];
    f4 xb = xr[it * 128 + 64 + lane];
    ba = bvs[it * 128 + lane];
    bb = bvs[it * 128 + 64 + lane];
    acc0 += xa.x * ba.x + xa.y * ba.y + xa.z * ba.z + xa.w * ba.w;
    acc1 += xb.x * bb.x + xb.y * bb.y + xb.z * bb.z + xb.w * bb.w;
  }
  float acc = acc0 + acc1;
#pragma unroll
  for (int off = 32; off > 0; off >>= 1) acc += __shfl_down(acc, off, 64);
  __shared__ float tv[8];
  if (lane == 0) {
    t[row] = acc;
    tv[wave] = acc;
  }
  __syncthreads();
  if (tid == 0) {
    double s = 0.0, q = 0.0;
#pragma unroll
    for (int w = 0; w < 8; ++w) {
      double v = (double)tv[w];
      s += v;
      q += v * v;
    }
    partials[blockIdx.x] = make_double2(s, q);
  }
}

// ---------------- Kernel 3: finish = wave0-reduce + BN + leaky + write -------
// PROVEN round-11 kernel: 512 blocks x 512 threads, 32 rows each; all
// co-resident (2/CU). Wave 0 reduces all 2048 partials: 32 coalesced L2
// rounds + 6-round shfl tree -- no __syncthreads inside, no fences/atomics.
// Fixed order, identical inputs in every block -> bit-deterministic.
__global__ __launch_bounds__(512) void k_finish(
    const float* __restrict__ t, const double2* __restrict__ partials,
    const float* __restrict__ A, const float* __restrict__ gamma,
    const float* __restrict__ beta, float* __restrict__ out) {
  __shared__ double red[2];     // mean, var
  __shared__ float ss[Dout];
  __shared__ float bs[Dout];
  __shared__ float ts[32];
  int tid = threadIdx.x;
  if (tid >= 64 && tid < 96) ts[tid - 64] = t[blockIdx.x * 32 + (tid - 64)];
  if (tid < 64) {
    double ls = 0.0, lq = 0.0;
#pragma unroll
    for (int i = 0; i < NPART / 64; ++i) {   // 32 independent coalesced rounds
      double2 p = partials[tid + i * 64];
      ls += p.x;
      lq += p.y;
    }
#pragma unroll
    for (int off = 32; off > 0; off >>= 1) {
      ls += __shfl_down(ls, off, 64);
      lq += __shfl_down(lq, off, 64);
    }
    if (tid == 0) {
      double mean = ls / (double)B_;
      red[0] = mean;
      red[1] = lq / (double)B_ - mean * mean;  // biased, matches jnp.var
    }
  }
  __syncthreads();
  double mean = red[0];
  double var = red[1];
  if (tid < Dout) {
    float a = A[tid];
    float inv = rsqrtf((float)((double)a * (double)a * var) + BN_EPS);
    float sj = a * gamma[tid] * inv;
    ss[tid] = sj;
    bs[tid] = beta[tid] - (float)mean * sj;
  }
  __syncthreads();
#pragma unroll
  for (int j = 0; j < 4; ++j) {
    int idx = j * 512 + tid;     // 0..2047 = 32 rows x 64 f4
    int rin = idx >> 6;
    int c4 = idx & 63;
    int row = blockIdx.x * 32 + rin;
    float tvv = ts[rin];
    f4 sv = *reinterpret_cast<const f4*>(&ss[c4 * 4]);
    f4 bv = *reinterpret_cast<const f4*>(&bs[c4 * 4]);
    f4 o;
    o.x = tvv * sv.x + bv.x; o.x = (o.x >= 0.f) ? o.x : NEG_SLOPE * o.x;
    o.y = tvv * sv.y + bv.y; o.y = (o.y >= 0.f) ? o.y : NEG_SLOPE * o.y;
    o.z = tvv * sv.z + bv.z; o.z = (o.z >= 0.f) ? o.z : NEG_SLOPE * o.z;
    o.w = tvv * sv.w + bv.w; o.w = (o.w >= 0.f) ? o.w : NEG_SLOPE * o.w;
    reinterpret_cast<f4*>(out)[(size_t)row * (Dout / 4) + c4] = o;
  }
}

extern "C" void kernel_launch(void* const* d_in, const int* in_sizes, int n_in,
                              void* d_out, int out_size, void* d_ws, size_t ws_size,
                              hipStream_t stream) {
  const float* x      = (const float*)d_in[0];
  const float* alphas = (const float*)d_in[1];
  const float* cA     = (const float*)d_in[2];
  const float* cB     = (const float*)d_in[3];
  // d_in[4] = linear_bias: cancels exactly inside BatchNorm (out - mean).
  const float* gamma  = (const float*)d_in[5];
  const float* beta   = (const float*)d_in[6];
  float* out = (float*)d_out;
  float* ws  = (float*)d_ws;

  float*   Bv       = ws + WS_BV;
  float*   A        = ws + WS_A;
  float*   t        = ws + WS_T;
  double2* partials = reinterpret_cast<double2*>(ws + WS_PART);

  k_synth<<<1 + Din / 256, 256, 0, stream>>>(alphas, cA, cB, A, Bv);
  k_matvec<<<NPART, 512, 0, stream>>>(x, Bv, t, partials);
  k_finish<<<B_ / 32, 512, 0, stream>>>(t, partials, A, gamma, beta, out);
}

// Round 14
// 56.337 us; speedup vs baseline: 1.0728x; 1.0026x over previous
//
#include <hip/hip_runtime.h>

#define BN_EPS 1e-5f
#define NEG_SLOPE 0.2f

constexpr int B_ = 16384;
constexpr int Din = 4096;
constexpr int Dout = 256;
constexpr int D_RANK = 20;
constexpr int NPART = 2048;   // one partial per matvec block

typedef float f4 __attribute__((ext_vector_type(4)));

// ws layout (floats):
// [0, 4096)        : Bv
// [4096, 4352)     : A
// [4352, 20736)    : t (16384)
// [20736, 28928)   : partials: 2048 x double2 (byte 82944, 16B-aligned)
#define WS_BV 0
#define WS_A 4096
#define WS_T 4352
#define WS_PART 20736

// Final configuration (round 11 structure, best measured 56.08 us):
//   - rank-1 factorization: the reference GEMM x@W.T with W = A (x) Bv
//     collapses to t = x@Bv (268 MB stream, the roofline term), BN stats of
//     out[:,j] = t*A[j]+bias reduce to scalar stats of t (bias cancels in
//     out-mean), epilogue is out = leaky(t[i]*s[j] + b2[j]).
//   - 3 kernels, no fences/atomics/grid-sync anywhere. Measured on MI355X:
//     coop grid.sync = 4x slower, per-block threadfence+atomic = 3x slower,
//     per-block Bv recompute = +47us, 1024-thread matvec blocks = +4us,
//     zigzag / nontemporal / prefetch = neutral.
//   - matvec: ~44 us = ~6.1 TB/s on x, ~97% of the 6.29 TB/s read ceiling.

// ---------------- Kernel 1: synthesize A (Dout) and Bv (Din) -----------------
__global__ __launch_bounds__(256) void k_synth(
    const float* __restrict__ alphas, const float* __restrict__ cA,
    const float* __restrict__ cB, float* __restrict__ A, float* __restrict__ Bv) {
  __shared__ float al[D_RANK];
  int tid = threadIdx.x;
  if (tid < D_RANK) al[tid] = alphas[tid];
  __syncthreads();
  if (blockIdx.x == 0) {
    float s = 0.f;
#pragma unroll
    for (int d = 0; d < D_RANK; ++d) s += al[d] * cA[d * Dout + tid];
    A[tid] = s;
  } else {
    int k = (blockIdx.x - 1) * 256 + tid;
    float s = 0.f;
#pragma unroll
    for (int d = 0; d < D_RANK; ++d) s += al[d] * cB[k * D_RANK + d];
    Bv[k] = s;
  }
}

// ---------------- Kernel 2: t = x @ Bv + per-block (sum, sumsq) partial ------
// 512 threads = 8 waves, one row per wave, grid 2048 = 4 blocks/CU,
// 32 waves/CU. Bv staged in LDS so x is the only VMEM stream.
__global__ __launch_bounds__(512) void k_matvec(
    const float* __restrict__ x, const float* __restrict__ Bv,
    float* __restrict__ t, double2* __restrict__ partials) {
  __shared__ f4 bvs[Din / 4];   // 16 KiB
  int tid = threadIdx.x;
  const f4* bv = reinterpret_cast<const f4*>(Bv);
  bvs[tid] = bv[tid];
  bvs[tid + 512] = bv[tid + 512];
  __syncthreads();

  int wave = tid >> 6;   // 0..7
  int lane = tid & 63;
  int row = blockIdx.x * 8 + wave;
  const f4* xr = reinterpret_cast<const f4*>(x + (size_t)row * Din);
  float acc0 = 0.f, acc1 = 0.f;
#pragma unroll
  for (int it = 0; it < 8; ++it) {
    f4 xa = xr[it * 128 + lane];
    f4 xb = xr[it * 128 + 64 + lane];
    f4 ba = bvs[it * 128 + lane];
    f4 bb = bvs[it * 128 + 64 + lane];
    acc0 += xa.x * ba.x + xa.y * ba.y + xa.z * ba.z + xa.w * ba.w;
    acc1 += xb.x * bb.x + xb.y * bb.y + xb.z * bb.z + xb.w * bb.w;
  }
  float acc = acc0 + acc1;
#pragma unroll
  for (int off = 32; off > 0; off >>= 1) acc += __shfl_down(acc, off, 64);
  __shared__ float tv[8];
  if (lane == 0) {
    t[row] = acc;
    tv[wave] = acc;
  }
  __syncthreads();
  if (tid == 0) {
    double s = 0.0, q = 0.0;
#pragma unroll
    for (int w = 0; w < 8; ++w) {
      double v = (double)tv[w];
      s += v;
      q += v * v;
    }
    partials[blockIdx.x] = make_double2(s, q);
  }
}

// ---------------- Kernel 3: finish = wave0-reduce + BN + leaky + write -------
// 512 blocks x 512 threads, 32 rows each; all co-resident (2/CU), so the
// redundant per-block stats reduction is paid once, in parallel. Wave 0
// reduces all 2048 partials: 32 coalesced L2 rounds + 6-round shfl tree --
// no __syncthreads inside, no fences/atomics. Fixed order, identical inputs
// in every block -> bit-deterministic.
__global__ __launch_bounds__(512) void k_finish(
    const float* __restrict__ t, const double2* __restrict__ partials,
    const float* __restrict__ A, const float* __restrict__ gamma,
    const float* __restrict__ beta, float* __restrict__ out) {
  __shared__ double red[2];     // mean, var
  __shared__ float ss[Dout];
  __shared__ float bs[Dout];
  __shared__ float ts[32];
  int tid = threadIdx.x;
  if (tid >= 64 && tid < 96) ts[tid - 64] = t[blockIdx.x * 32 + (tid - 64)];
  if (tid < 64) {
    double ls = 0.0, lq = 0.0;
#pragma unroll
    for (int i = 0; i < NPART / 64; ++i) {   // 32 independent coalesced rounds
      double2 p = partials[tid + i * 64];
      ls += p.x;
      lq += p.y;
    }
#pragma unroll
    for (int off = 32; off > 0; off >>= 1) {
      ls += __shfl_down(ls, off, 64);
      lq += __shfl_down(lq, off, 64);
    }
    if (tid == 0) {
      double mean = ls / (double)B_;
      red[0] = mean;
      red[1] = lq / (double)B_ - mean * mean;  // biased, matches jnp.var
    }
  }
  __syncthreads();
  double mean = red[0];
  double var = red[1];
  if (tid < Dout) {
    float a = A[tid];
    float inv = rsqrtf((float)((double)a * (double)a * var) + BN_EPS);
    float sj = a * gamma[tid] * inv;
    ss[tid] = sj;
    bs[tid] = beta[tid] - (float)mean * sj;
  }
  __syncthreads();
#pragma unroll
  for (int j = 0; j < 4; ++j) {
    int idx = j * 512 + tid;     // 0..2047 = 32 rows x 64 f4
    int rin = idx >> 6;
    int c4 = idx & 63;
    int row = blockIdx.x * 32 + rin;
    float tvv = ts[rin];
    f4 sv = *reinterpret_cast<const f4*>(&ss[c4 * 4]);
    f4 bv = *reinterpret_cast<const f4*>(&bs[c4 * 4]);
    f4 o;
    o.x = tvv * sv.x + bv.x; o.x = (o.x >= 0.f) ? o.x : NEG_SLOPE * o.x;
    o.y = tvv * sv.y + bv.y; o.y = (o.y >= 0.f) ? o.y : NEG_SLOPE * o.y;
    o.z = tvv * sv.z + bv.z; o.z = (o.z >= 0.f) ? o.z : NEG_SLOPE * o.z;
    o.w = tvv * sv.w + bv.w; o.w = (o.w >= 0.f) ? o.w : NEG_SLOPE * o.w;
    reinterpret_cast<f4*>(out)[(size_t)row * (Dout / 4) + c4] = o;
  }
}

extern "C" void kernel_launch(void* const* d_in, const int* in_sizes, int n_in,
                              void* d_out, int out_size, void* d_ws, size_t ws_size,
                              hipStream_t stream) {
  const float* x      = (const float*)d_in[0];
  const float* alphas = (const float*)d_in[1];
  const float* cA     = (const float*)d_in[2];
  const float* cB     = (const float*)d_in[3];
  // d_in[4] = linear_bias: cancels exactly inside BatchNorm (out - mean).
  const float* gamma  = (const float*)d_in[5];
  const float* beta   = (const float*)d_in[6];
  float* out = (float*)d_out;
  float* ws  = (float*)d_ws;

  float*   Bv       = ws + WS_BV;
  float*   A        = ws + WS_A;
  float*   t        = ws + WS_T;
  double2* partials = reinterpret_cast<double2*>(ws + WS_PART);

  k_synth<<<1 + Din / 256, 256, 0, stream>>>(alphas, cA, cB, A, Bv);
  k_matvec<<<NPART, 512, 0, stream>>>(x, Bv, t, partials);
  k_finish<<<B_ / 32, 512, 0, stream>>>(t, partials, A, gamma, beta, out);
}